// Round 2
// baseline (275.982 us; speedup 1.0000x reference)
//
#include <hip/hip_runtime.h>

constexpr int B = 1024, N = 40, ETA_D = 64, K = 32, ZD = 32, NA = 10, NB = 5;
constexpr int CH = 128, AH = 128, BH = 64;
constexpr int NNODE = B * N;            // 40960
constexpr int NPAIR = N * (N - 1) / 2;  // 780
constexpr int ZPAD = 36;                // padded row stride (floats) to break bank conflicts

// ---------------- kernel 1: cluster head -> log_pi (fp32, ws) ----------------
__global__ __launch_bounds__(256) void cluster_kernel(
    const float* __restrict__ eta, const float* __restrict__ cW1, const float* __restrict__ cb1,
    const float* __restrict__ cW2, const float* __restrict__ cb2,
    const float* __restrict__ cWs, const float* __restrict__ cbs,
    float* __restrict__ log_pi)
{
  const int lane = threadIdx.x & 63, wid = threadIdx.x >> 6;
  const int row = blockIdx.x * 4 + wid;
  __shared__ __align__(16) float etas[4][64];
  __shared__ __align__(16) float hs[4][128];
  etas[wid][lane] = eta[row * 64 + lane];
  __syncthreads();
  float a0 = cb1[lane], a1 = cb1[lane + 64];
  for (int d = 0; d < 64; ++d) {
    float ed = etas[wid][d];
    a0 += ed * cW1[d * 128 + lane];
    a1 += ed * cW1[d * 128 + lane + 64];
  }
  hs[wid][lane] = fmaxf(a0, 0.f);
  hs[wid][lane + 64] = fmaxf(a1, 0.f);
  __syncthreads();
  if (lane < 32) {
    float x = cb2[lane] + cbs[lane];
    for (int j = 0; j < 128; ++j) x += hs[wid][j] * cW2[j * 32 + lane];
    for (int d = 0; d < 64; ++d) x += etas[wid][d] * cWs[d * 32 + lane];
    float m = x;
    for (int off = 16; off; off >>= 1) m = fmaxf(m, __shfl_xor(m, off));
    float e = __expf(x - m);
    float s = e;
    for (int off = 16; off; off >>= 1) s += __shfl_xor(s, off);
    log_pi[row * 32 + lane] = (x - m) - __logf(s);
  }
}

// ---------------- kernel 2: argmax, z, atom resblock ----------------
__global__ __launch_bounds__(256) void node_kernel(
    const float* __restrict__ log_pi, const float* __restrict__ gumbel,
    const float* __restrict__ z_noise,
    const float* __restrict__ means, const float* __restrict__ log_sig,
    const float* __restrict__ aW1, const float* __restrict__ ab1,
    const float* __restrict__ aW2, const float* __restrict__ ab2,
    const float* __restrict__ aWs, const float* __restrict__ abs_,
    float* __restrict__ z_out, float* __restrict__ atom_out)
{
  const int lane = threadIdx.x & 63, wid = threadIdx.x >> 6;
  const int node = blockIdx.x * 4 + wid;
  const int brow = node / N;
  __shared__ __align__(16) float zs[4][32];

  // argmax over 32 of log_pi[brow] + gumbel[node]; first-index tie-break
  float v = -3.0e38f;
  int kidx = 0;
  if (lane < 32) {
    v = log_pi[brow * 32 + lane] + gumbel[node * 32 + lane];
    kidx = lane;
  }
  for (int off = 32; off; off >>= 1) {
    float ov = __shfl_xor(v, off);
    int oi = __shfl_xor(kidx, off);
    if (ov > v || (ov == v && oi < kidx)) { v = ov; kidx = oi; }
  }
  const int k = kidx;  // uniform across the wave

  if (lane < 32) {
    float mu = means[k * 32 + lane];
    float ls = log_sig[k * 32 + lane];
    ls = fminf(fmaxf(ls, -20.f), 30.f);
    float zv = z_noise[node * 32 + lane] * __expf(ls) + mu;
    zs[wid][lane] = zv;
    z_out[node * 32 + lane] = zv;
  }
  __syncthreads();

  // h = relu(z @ aW1 + ab1): lane owns h[lane], h[lane+64]
  float a0 = ab1[lane], a1 = ab1[lane + 64];
  for (int c = 0; c < 32; ++c) {
    float zc = zs[wid][c];
    a0 += zc * aW1[c * 128 + lane];
    a1 += zc * aW1[c * 128 + lane + 64];
  }
  float h0 = fmaxf(a0, 0.f), h1 = fmaxf(a1, 0.f);

  for (int k2 = 0; k2 < NA; ++k2) {
    float val = h0 * aW2[lane * 10 + k2] + h1 * aW2[(lane + 64) * 10 + k2];
    if (lane < 32) val += zs[wid][lane] * aWs[lane * 10 + k2];
    for (int off = 32; off; off >>= 1) val += __shfl_xor(val, off);
    if (lane == 0)
      atom_out[node * 10 + k2] = val + ab2[k2] + abs_[k2];
  }
}

// ---------------- kernel 3: per-molecule bilinear + edge head ----------------
__global__ __launch_bounds__(256) void edge_kernel(
    const float* __restrict__ z, const float* __restrict__ bond,
    const float* __restrict__ bW1, const float* __restrict__ bb1,
    const float* __restrict__ bW2, const float* __restrict__ bb2,
    const float* __restrict__ bWs, const float* __restrict__ bbs,
    float* __restrict__ edge_out)
{
  __shared__ __align__(16) float Zs[N * ZPAD];       // 40x36
  __shared__ __align__(16) float Us[NB * N * ZPAD];  // 5x40x36
  __shared__ __align__(16) float Ws[NB * 32 * 32];   // Wsym; aliased with head weights later
  const int tid = threadIdx.x;
  const int mol = blockIdx.x;

  for (int e = tid; e < N * 32; e += 256) {
    int i = e >> 5, c = e & 31;
    Zs[i * ZPAD + c] = z[(mol * N + i) * 32 + c];
  }
  for (int e = tid; e < NB * 1024; e += 256) {
    int t = e >> 10, r = e & 1023, c = r >> 5, d = r & 31;
    Ws[e] = 0.5f * (bond[t * 1024 + c * 32 + d] + bond[t * 1024 + d * 32 + c]);
  }
  __syncthreads();

  // U[t][i][d] = sum_c Z[i][c] * Wsym[t][c][d]; thread owns (t,i)
  if (tid < NB * N) {
    const int t = tid / N, i = tid - t * N;
    float zr[32];
    const float4* z4 = (const float4*)&Zs[i * ZPAD];
    for (int c4 = 0; c4 < 8; ++c4) {
      float4 q = z4[c4];
      zr[4 * c4] = q.x; zr[4 * c4 + 1] = q.y; zr[4 * c4 + 2] = q.z; zr[4 * c4 + 3] = q.w;
    }
    float acc[32];
    for (int d = 0; d < 32; ++d) acc[d] = 0.f;
    for (int c = 0; c < 32; ++c) {
      float zc = zr[c];
      const float4* w4 = (const float4*)&Ws[t * 1024 + c * 32];
      for (int d4 = 0; d4 < 8; ++d4) {
        float4 w = w4[d4];
        acc[4 * d4] += zc * w.x; acc[4 * d4 + 1] += zc * w.y;
        acc[4 * d4 + 2] += zc * w.z; acc[4 * d4 + 3] += zc * w.w;
      }
    }
    float4* u4 = (float4*)&Us[(t * N + i) * ZPAD];
    for (int d4 = 0; d4 < 8; ++d4)
      u4[d4] = make_float4(acc[4 * d4], acc[4 * d4 + 1], acc[4 * d4 + 2], acc[4 * d4 + 3]);
  }
  __syncthreads();

  // head weights aliased into Ws (done with Wsym now)
  float* w1h = Ws;         // [5][64]
  float* b1h = Ws + 320;   // [64]
  float* w2t = Ws + 384;   // [5][64] = bW2 transposed
  float* b2h = Ws + 704;   // [5]
  float* wsh = Ws + 709;   // [5][5]
  float* bsh = Ws + 734;   // [5]
  for (int idx = tid; idx < 739; idx += 256) {
    if (idx < 320) w1h[idx] = bW1[idx];
    else if (idx < 384) b1h[idx - 320] = bb1[idx - 320];
    else if (idx < 704) { int q = idx - 384; int t2 = q >> 6, j = q & 63; w2t[t2 * 64 + j] = bW2[j * 5 + t2]; }
    else if (idx < 709) b2h[idx - 704] = bb2[idx - 704];
    else if (idx < 734) wsh[idx - 709] = bWs[idx - 709];
    else bsh[idx - 734] = bbs[idx - 734];
  }
  __syncthreads();

  for (int p = tid; p < NPAIR; p += 256) {
    int i = 0, rem = p;
    while (rem >= (N - 1 - i)) { rem -= (N - 1 - i); ++i; }
    const int j = i + 1 + rem;

    float4 zj[8];
    const float4* zj4 = (const float4*)&Zs[j * ZPAD];
    for (int c4 = 0; c4 < 8; ++c4) zj[c4] = zj4[c4];

    float bil[5];
    for (int t = 0; t < 5; ++t) {
      const float4* u4 = (const float4*)&Us[(t * N + i) * ZPAD];
      float acc = 0.f;
      for (int c4 = 0; c4 < 8; ++c4) {
        float4 u = u4[c4];
        acc += u.x * zj[c4].x + u.y * zj[c4].y + u.z * zj[c4].z + u.w * zj[c4].w;
      }
      bil[t] = acc;
    }

    float lg[5];
    for (int t2 = 0; t2 < 5; ++t2) {
      float a = b2h[t2] + bsh[t2];
      for (int t = 0; t < 5; ++t) a += bil[t] * wsh[t * 5 + t2];
      lg[t2] = a;
    }
    for (int j4 = 0; j4 < 16; ++j4) {
      float4 h = ((const float4*)b1h)[j4];
      for (int t = 0; t < 5; ++t) {
        float4 w = ((const float4*)(w1h + t * 64))[j4];
        h.x += bil[t] * w.x; h.y += bil[t] * w.y; h.z += bil[t] * w.z; h.w += bil[t] * w.w;
      }
      h.x = fmaxf(h.x, 0.f); h.y = fmaxf(h.y, 0.f); h.z = fmaxf(h.z, 0.f); h.w = fmaxf(h.w, 0.f);
      for (int t2 = 0; t2 < 5; ++t2) {
        float4 w = ((const float4*)(w2t + t2 * 64))[j4];
        lg[t2] += h.x * w.x + h.y * w.y + h.z * w.z + h.w * w.w;
      }
    }

    float m = lg[0];
    for (int t2 = 1; t2 < 5; ++t2) m = fmaxf(m, lg[t2]);
    float e[5], s = 0.f;
    for (int t2 = 0; t2 < 5; ++t2) { e[t2] = __expf(lg[t2] - m); s += e[t2]; }
    float inv = 1.f / s;
    float* outp = edge_out + (size_t)(mol * NPAIR + p) * 5;
    for (int t2 = 0; t2 < 5; ++t2) outp[t2] = e[t2] * inv;
  }
}

extern "C" void kernel_launch(void* const* d_in, const int* in_sizes, int n_in,
                              void* d_out, int out_size, void* d_ws, size_t ws_size,
                              hipStream_t stream) {
  const float* eta    = (const float*)d_in[0];
  const float* gumbel = (const float*)d_in[1];
  const float* z_noise= (const float*)d_in[2];
  const float* cW1 = (const float*)d_in[3];
  const float* cb1 = (const float*)d_in[4];
  const float* cW2 = (const float*)d_in[5];
  const float* cb2 = (const float*)d_in[6];
  const float* cWs = (const float*)d_in[7];
  const float* cbs = (const float*)d_in[8];
  const float* means = (const float*)d_in[9];
  const float* lsig  = (const float*)d_in[10];
  const float* aW1 = (const float*)d_in[11];
  const float* ab1 = (const float*)d_in[12];
  const float* aW2 = (const float*)d_in[13];
  const float* ab2 = (const float*)d_in[14];
  const float* aWs = (const float*)d_in[15];
  const float* abs_= (const float*)d_in[16];
  const float* bond= (const float*)d_in[17];
  const float* bW1 = (const float*)d_in[18];
  const float* bb1 = (const float*)d_in[19];
  const float* bW2 = (const float*)d_in[20];
  const float* bb2 = (const float*)d_in[21];
  const float* bWs = (const float*)d_in[22];
  const float* bbs = (const float*)d_in[23];

  float* log_pi = (float*)d_ws;            // 1024*32 fp32
  float* zbuf   = log_pi + B * K;          // 40960*32 fp32
  float* atom_out = (float*)d_out;         // 409600
  float* edge_out = atom_out + NNODE * NA; // 3993600

  cluster_kernel<<<B / 4, 256, 0, stream>>>(eta, cW1, cb1, cW2, cb2, cWs, cbs, log_pi);
  node_kernel<<<NNODE / 4, 256, 0, stream>>>(log_pi, gumbel, z_noise, means, lsig,
                                             aW1, ab1, aW2, ab2, aWs, abs_, zbuf, atom_out);
  edge_kernel<<<B, 256, 0, stream>>>(zbuf, bond, bW1, bb1, bW2, bb2, bWs, bbs, edge_out);
}

// Round 3
// 235.761 us; speedup vs baseline: 1.1706x; 1.1706x over previous
//
#include <hip/hip_runtime.h>

constexpr int B = 1024, N = 40, K = 32, ZD = 32, NA = 10, NBOND = 5;
constexpr int NNODE = B * N;            // 40960
constexpr int NPAIR = N * (N - 1) / 2;  // 780
constexpr int ZPAD = 36;

// ---------------- kernel 1: cluster head -> log_pi (fp32, ws) ----------------
__global__ __launch_bounds__(256) void cluster_kernel(
    const float* __restrict__ eta, const float* __restrict__ cW1, const float* __restrict__ cb1,
    const float* __restrict__ cW2, const float* __restrict__ cb2,
    const float* __restrict__ cWs, const float* __restrict__ cbs,
    float* __restrict__ log_pi)
{
  const int lane = threadIdx.x & 63, wid = threadIdx.x >> 6;
  const int row = blockIdx.x * 4 + wid;
  __shared__ __align__(16) float etas[4][64];
  __shared__ __align__(16) float hs[4][128];
  etas[wid][lane] = eta[row * 64 + lane];
  __syncthreads();
  float a0 = cb1[lane], a1 = cb1[lane + 64];
  for (int d = 0; d < 64; ++d) {
    float ed = etas[wid][d];
    a0 += ed * cW1[d * 128 + lane];
    a1 += ed * cW1[d * 128 + lane + 64];
  }
  hs[wid][lane] = fmaxf(a0, 0.f);
  hs[wid][lane + 64] = fmaxf(a1, 0.f);
  __syncthreads();
  if (lane < 32) {
    float x = cb2[lane] + cbs[lane];
    for (int j = 0; j < 128; ++j) x += hs[wid][j] * cW2[j * 32 + lane];
    for (int d = 0; d < 64; ++d) x += etas[wid][d] * cWs[d * 32 + lane];
    float m = x;
    for (int off = 16; off; off >>= 1) m = fmaxf(m, __shfl_xor(m, off));
    float e = __expf(x - m);
    float s = e;
    for (int off = 16; off; off >>= 1) s += __shfl_xor(s, off);
    log_pi[row * 32 + lane] = (x - m) - __logf(s);
  }
}

// ---------------- kernel 2: thread-per-node, weights in LDS ----------------
// grid: 256 blocks x 256 threads; block b handles nodes [b*160, b*160+160)
__global__ __launch_bounds__(256) void node_kernel(
    const float* __restrict__ log_pi, const float* __restrict__ gumbel,
    const float* __restrict__ z_noise,
    const float* __restrict__ means, const float* __restrict__ log_sig,
    const float* __restrict__ aW1, const float* __restrict__ ab1,
    const float* __restrict__ aW2, const float* __restrict__ ab2,
    const float* __restrict__ aWs, const float* __restrict__ abs_,
    float* __restrict__ z_out, float* __restrict__ atom_out)
{
  __shared__ __align__(16) float W1T[128 * ZPAD];  // W1T[j][c] = aW1[c*128+j]
  __shared__ __align__(16) float W2p[128 * 12];    // W2p[j][k] = aW2[j*10+k]
  __shared__ __align__(16) float Wsp[32 * 12];     // Wsp[c][k] = aWs[c*10+k]
  __shared__ __align__(16) float mpad[32 * ZPAD];
  __shared__ __align__(16) float spad[32 * ZPAD];  // exp(clamp(log_sigma))
  __shared__ float b1s[128];
  __shared__ float b2s[12];
  __shared__ float lps[4 * 32];
  const int tid = threadIdx.x;

  for (int t = tid; t < 32 * 128; t += 256) { int c = t >> 7, j = t & 127; W1T[j * ZPAD + c] = aW1[t]; }
  for (int t = tid; t < 1280; t += 256)     { int j = t / 10, k2 = t - j * 10; W2p[j * 12 + k2] = aW2[t]; }
  for (int t = tid; t < 320; t += 256)      { int c = t / 10, k2 = t - c * 10; Wsp[c * 12 + k2] = aWs[t]; }
  for (int t = tid; t < 1024; t += 256) {
    int kk = t >> 5, c = t & 31;
    mpad[kk * ZPAD + c] = means[t];
    float ls = log_sig[t];
    spad[kk * ZPAD + c] = __expf(fminf(fmaxf(ls, -20.f), 30.f));
  }
  if (tid < 128) b1s[tid] = ab1[tid];
  if (tid < 10)  b2s[tid] = ab2[tid] + abs_[tid];
  const int n0 = blockIdx.x * 160;          // divisible by 40 -> 4 log_pi rows
  const int r0 = n0 / 40;
  if (tid < 128) lps[tid] = log_pi[(r0 + (tid >> 5)) * 32 + (tid & 31)];
  __syncthreads();

  if (tid >= 160) return;
  const int n = n0 + tid;
  const float* lp = &lps[(tid / 40) * 32];

  // argmax of lp + gumbel (first-index tie-break)
  float g[32];
  {
    const float4* g4 = (const float4*)(gumbel + (size_t)n * 32);
    for (int q = 0; q < 8; ++q) {
      float4 v = g4[q];
      g[4 * q] = v.x; g[4 * q + 1] = v.y; g[4 * q + 2] = v.z; g[4 * q + 3] = v.w;
    }
  }
  int kbest = 0;
  float vbest = lp[0] + g[0];
  for (int c = 1; c < 32; ++c) {
    float v = lp[c] + g[c];
    if (v > vbest) { vbest = v; kbest = c; }
  }

  // z = z_noise * sigma[k] + mu[k]
  float z[32];
  {
    const float4* zn4 = (const float4*)(z_noise + (size_t)n * 32);
    const float* mk = &mpad[kbest * ZPAD];
    const float* sk = &spad[kbest * ZPAD];
    float4* zo4 = (float4*)(z_out + (size_t)n * 32);
    for (int q = 0; q < 8; ++q) {
      float4 v = zn4[q];
      float4 zz;
      zz.x = v.x * sk[4 * q]     + mk[4 * q];
      zz.y = v.y * sk[4 * q + 1] + mk[4 * q + 1];
      zz.z = v.z * sk[4 * q + 2] + mk[4 * q + 2];
      zz.w = v.w * sk[4 * q + 3] + mk[4 * q + 3];
      z[4 * q] = zz.x; z[4 * q + 1] = zz.y; z[4 * q + 2] = zz.z; z[4 * q + 3] = zz.w;
      zo4[q] = zz;
    }
  }

  float acc[10];
  for (int k2 = 0; k2 < 10; ++k2) acc[k2] = b2s[k2];
  // skip connection: z @ aWs
  for (int c = 0; c < 32; ++c) {
    float zc = z[c];
    const float4* w = (const float4*)&Wsp[c * 12];
    float4 w0 = w[0], w1 = w[1], w2 = w[2];
    acc[0] += zc * w0.x; acc[1] += zc * w0.y; acc[2] += zc * w0.z; acc[3] += zc * w0.w;
    acc[4] += zc * w1.x; acc[5] += zc * w1.y; acc[6] += zc * w1.z; acc[7] += zc * w1.w;
    acc[8] += zc * w2.x; acc[9] += zc * w2.y;
  }
  // main: h_j = relu(b1 + z . W1T[j]), acc += h_j * W2[j]
  for (int j = 0; j < 128; ++j) {
    const float4* w = (const float4*)&W1T[j * ZPAD];
    float h = b1s[j];
    for (int q = 0; q < 8; ++q) {
      float4 wv = w[q];
      h += z[4 * q] * wv.x + z[4 * q + 1] * wv.y + z[4 * q + 2] * wv.z + z[4 * q + 3] * wv.w;
    }
    h = fmaxf(h, 0.f);
    const float4* w2 = (const float4*)&W2p[j * 12];
    float4 a0 = w2[0], a1 = w2[1], a2 = w2[2];
    acc[0] += h * a0.x; acc[1] += h * a0.y; acc[2] += h * a0.z; acc[3] += h * a0.w;
    acc[4] += h * a1.x; acc[5] += h * a1.y; acc[6] += h * a1.z; acc[7] += h * a1.w;
    acc[8] += h * a2.x; acc[9] += h * a2.y;
  }
  float* outp = atom_out + (size_t)n * 10;
  for (int k2 = 0; k2 < 10; ++k2) outp[k2] = acc[k2];
}

// ---------------- kernel 3: per-molecule bilinear + edge head ----------------
__global__ __launch_bounds__(256) void edge_kernel(
    const float* __restrict__ z, const float* __restrict__ bond,
    const float* __restrict__ bW1, const float* __restrict__ bb1,
    const float* __restrict__ bW2, const float* __restrict__ bb2,
    const float* __restrict__ bWs, const float* __restrict__ bbs,
    float* __restrict__ edge_out)
{
  __shared__ __align__(16) float Zs[N * ZPAD];         // 40x36
  __shared__ __align__(16) float Us[NBOND * N * ZPAD]; // 5x40x36
  __shared__ __align__(16) float Wsp[5 * 1156];        // Wsym, plane stride 1156; later head weights
  const int tid = threadIdx.x;
  const int mol = blockIdx.x;

  for (int e = tid; e < N * 32; e += 256) {
    int i = e >> 5, c = e & 31;
    Zs[i * ZPAD + c] = z[(size_t)(mol * N + i) * 32 + c];
  }
  for (int e = tid; e < 5120; e += 256) {
    int t = e >> 10, r = e & 1023, c = r >> 5, d = r & 31;
    Wsp[t * 1156 + c * ZPAD + d] = 0.5f * (bond[t * 1024 + c * 32 + d] + bond[t * 1024 + d * 32 + c]);
  }
  __syncthreads();

  // U[t][i][:] = Z[i] @ Wsym[t]; 400 units (t, i, half16)
  for (int u = tid; u < 400; u += 256) {
    int t = u / 80, r2 = u - t * 80, i = r2 >> 1, half = r2 & 1;
    const float* zrow = &Zs[i * ZPAD];
    float4 a0 = make_float4(0.f, 0.f, 0.f, 0.f), a1 = a0, a2 = a0, a3 = a0;
    const float* wbase = &Wsp[t * 1156 + half * 16];
    for (int c = 0; c < 32; ++c) {
      float zc = zrow[c];
      const float4* w4 = (const float4*)(wbase + c * ZPAD);
      float4 w0 = w4[0], w1 = w4[1], w2 = w4[2], w3 = w4[3];
      a0.x += zc * w0.x; a0.y += zc * w0.y; a0.z += zc * w0.z; a0.w += zc * w0.w;
      a1.x += zc * w1.x; a1.y += zc * w1.y; a1.z += zc * w1.z; a1.w += zc * w1.w;
      a2.x += zc * w2.x; a2.y += zc * w2.y; a2.z += zc * w2.z; a2.w += zc * w2.w;
      a3.x += zc * w3.x; a3.y += zc * w3.y; a3.z += zc * w3.z; a3.w += zc * w3.w;
    }
    float4* u4 = (float4*)&Us[(t * N + i) * ZPAD + half * 16];
    u4[0] = a0; u4[1] = a1; u4[2] = a2; u4[3] = a3;
  }
  __syncthreads();

  // head weights overwrite Wsp
  float* w1h = Wsp;         // [5][64]
  float* b1h = Wsp + 320;   // [64]
  float* w2t = Wsp + 384;   // [5][64] = bW2^T
  float* b2h = Wsp + 704;   // [5]
  float* wsh = Wsp + 709;   // [5][5]
  float* bsh = Wsp + 734;   // [5]
  for (int idx = tid; idx < 739; idx += 256) {
    if (idx < 320) w1h[idx] = bW1[idx];
    else if (idx < 384) b1h[idx - 320] = bb1[idx - 320];
    else if (idx < 704) { int q = idx - 384; int t2 = q >> 6, j = q & 63; w2t[t2 * 64 + j] = bW2[j * 5 + t2]; }
    else if (idx < 709) b2h[idx - 704] = bb2[idx - 704];
    else if (idx < 734) wsh[idx - 709] = bWs[idx - 709];
    else bsh[idx - 734] = bbs[idx - 734];
  }

  // bilinear for up to 4 owned pairs (reads Us/Zs, independent of Wsp rewrite)
  float bil[4][5];
  int pj[4];
  for (int pp = 0; pp < 4; ++pp) {
    int p = tid + pp * 256;
    if (p < NPAIR) {
      int i = (int)(39.5f - sqrtf(1560.25f - 2.f * (float)p));
      int S = i * (79 - i) / 2;
      if (p < S) { --i; S = i * (79 - i) / 2; }
      else if (p >= S + (39 - i)) { ++i; S = i * (79 - i) / 2; }
      int j = i + 1 + (p - S);
      pj[pp] = j;  (void)pj;
      float4 zj[8];
      const float4* zj4 = (const float4*)&Zs[j * ZPAD];
      for (int q = 0; q < 8; ++q) zj[q] = zj4[q];
      for (int t = 0; t < 5; ++t) {
        const float4* u4 = (const float4*)&Us[(t * N + i) * ZPAD];
        float s = 0.f;
        for (int q = 0; q < 8; ++q) {
          float4 u = u4[q];
          s += u.x * zj[q].x + u.y * zj[q].y + u.z * zj[q].z + u.w * zj[q].w;
        }
        bil[pp][t] = s;
      }
    } else {
      for (int t = 0; t < 5; ++t) bil[pp][t] = 0.f;
    }
  }
  __syncthreads();

  // head: lg = b2 + bs + bil@Ws + relu(b1 + bil@W1) @ W2
  float lg[4][5];
  for (int pp = 0; pp < 4; ++pp)
    for (int t2 = 0; t2 < 5; ++t2) {
      float a = b2h[t2] + bsh[t2];
      for (int t = 0; t < 5; ++t) a += bil[pp][t] * wsh[t * 5 + t2];
      lg[pp][t2] = a;
    }
  for (int j4 = 0; j4 < 16; ++j4) {
    float4 bb = ((const float4*)b1h)[j4];
    float4 w1v[5], w2v[5];
    for (int t = 0; t < 5; ++t) { w1v[t] = ((const float4*)(w1h + t * 64))[j4]; w2v[t] = ((const float4*)(w2t + t * 64))[j4]; }
    for (int pp = 0; pp < 4; ++pp) {
      float4 h = bb;
      for (int t = 0; t < 5; ++t) {
        float bt = bil[pp][t];
        h.x += bt * w1v[t].x; h.y += bt * w1v[t].y; h.z += bt * w1v[t].z; h.w += bt * w1v[t].w;
      }
      h.x = fmaxf(h.x, 0.f); h.y = fmaxf(h.y, 0.f); h.z = fmaxf(h.z, 0.f); h.w = fmaxf(h.w, 0.f);
      for (int t2 = 0; t2 < 5; ++t2) {
        lg[pp][t2] += h.x * w2v[t2].x + h.y * w2v[t2].y + h.z * w2v[t2].z + h.w * w2v[t2].w;
      }
    }
  }

  for (int pp = 0; pp < 4; ++pp) {
    int p = tid + pp * 256;
    if (p >= NPAIR) continue;
    float m = lg[pp][0];
    for (int t2 = 1; t2 < 5; ++t2) m = fmaxf(m, lg[pp][t2]);
    float e[5], s = 0.f;
    for (int t2 = 0; t2 < 5; ++t2) { e[t2] = __expf(lg[pp][t2] - m); s += e[t2]; }
    float inv = 1.f / s;
    float* outp = edge_out + (size_t)(mol * NPAIR + p) * 5;
    for (int t2 = 0; t2 < 5; ++t2) outp[t2] = e[t2] * inv;
  }
}

extern "C" void kernel_launch(void* const* d_in, const int* in_sizes, int n_in,
                              void* d_out, int out_size, void* d_ws, size_t ws_size,
                              hipStream_t stream) {
  const float* eta    = (const float*)d_in[0];
  const float* gumbel = (const float*)d_in[1];
  const float* z_noise= (const float*)d_in[2];
  const float* cW1 = (const float*)d_in[3];
  const float* cb1 = (const float*)d_in[4];
  const float* cW2 = (const float*)d_in[5];
  const float* cb2 = (const float*)d_in[6];
  const float* cWs = (const float*)d_in[7];
  const float* cbs = (const float*)d_in[8];
  const float* means = (const float*)d_in[9];
  const float* lsig  = (const float*)d_in[10];
  const float* aW1 = (const float*)d_in[11];
  const float* ab1 = (const float*)d_in[12];
  const float* aW2 = (const float*)d_in[13];
  const float* ab2 = (const float*)d_in[14];
  const float* aWs = (const float*)d_in[15];
  const float* abs_= (const float*)d_in[16];
  const float* bond= (const float*)d_in[17];
  const float* bW1 = (const float*)d_in[18];
  const float* bb1 = (const float*)d_in[19];
  const float* bW2 = (const float*)d_in[20];
  const float* bb2 = (const float*)d_in[21];
  const float* bWs = (const float*)d_in[22];
  const float* bbs = (const float*)d_in[23];

  float* log_pi = (float*)d_ws;            // 1024*32 fp32
  float* zbuf   = log_pi + B * K;          // 40960*32 fp32
  float* atom_out = (float*)d_out;
  float* edge_out = atom_out + NNODE * NA;

  cluster_kernel<<<B / 4, 256, 0, stream>>>(eta, cW1, cb1, cW2, cb2, cWs, cbs, log_pi);
  node_kernel<<<256, 256, 0, stream>>>(log_pi, gumbel, z_noise, means, lsig,
                                       aW1, ab1, aW2, ab2, aWs, abs_, zbuf, atom_out);
  edge_kernel<<<B, 256, 0, stream>>>(zbuf, bond, bW1, bb1, bW2, bb2, bWs, bbs, edge_out);
}